// Round 5
// baseline (284.807 us; speedup 1.0000x reference)
//
#include <hip/hip_runtime.h>
#include <hip/hip_cooperative_groups.h>

namespace cg = cooperative_groups;

#define CB 256   // batch
#define CR 1152  // routes
#define CC 10    // class capsules
#define CO 16    // out dim
#define CI 8     // in dim
#define CK (CR*CI)   // 9216
#define NCO (CC*CO)  // 160
#define GRD 256
#define THR 512

typedef __bf16 bf16_t;
typedef __attribute__((ext_vector_type(8))) __bf16 bf16x8;
typedef __attribute__((ext_vector_type(4))) float f32x4;

union SMem {
  float Ls[8][64][4];                 // s-phase partial store (8 KB)
  unsigned short vL[NCO][CB + 8];     // asc-phase v staging (84.5 KB)
};

__global__ __launch_bounds__(THR, 1) void k_fused(
    const float* __restrict__ x, const float* __restrict__ W,
    const float* __restrict__ bias, float* __restrict__ out,
    bf16_t* __restrict__ xb, bf16_t* __restrict__ xTb,
    bf16_t* __restrict__ Wt, bf16_t* __restrict__ Wts,
    bf16_t* __restrict__ vTb) {
  cg::grid_group grid = cg::this_grid();
  __shared__ SMem sm;
  __shared__ float bL[8][CC];    // persistent routing logits for this block's 8 r's
  __shared__ float agrL[8][CC];
  __shared__ float cwL[8][CC];

  const int blk = blockIdx.x;
  const int t = threadIdx.x;

  // ---------------- phase 0: convert x->xb [b][k], x->xTb [k][b], W->Wt [co][k] ----------------
  for (int job = blk; job < 1512; job += GRD) {
    if (job < 576) {                       // xb: 294912 bf16x8 slots
      const int vi = job * THR + t;
      const float4 f0 = ((const float4*)x)[vi * 2];
      const float4 f1 = ((const float4*)x)[vi * 2 + 1];
      bf16x8 ov;
      ov[0] = (bf16_t)f0.x; ov[1] = (bf16_t)f0.y; ov[2] = (bf16_t)f0.z; ov[3] = (bf16_t)f0.w;
      ov[4] = (bf16_t)f1.x; ov[5] = (bf16_t)f1.y; ov[6] = (bf16_t)f1.z; ov[7] = (bf16_t)f1.w;
      ((bf16x8*)xb)[vi] = ov;
    } else if (job < 1152) {               // xTb: 9216 k x 32 b-groups
      const int u = (job - 576) * THR + t;
      const int bg = u / 9216;
      const int k = u - bg * 9216;
      const int b0 = bg * 8;
      bf16x8 tv;
      #pragma unroll
      for (int j = 0; j < 8; ++j) tv[j] = (bf16_t)x[(size_t)(b0 + j) * CK + k];
      *(bf16x8*)(xTb + (size_t)k * CB + b0) = tv;
    } else {                               // Wt: 184320 co*r slots
      const int wi = (job - 1152) * THR + t;
      const int r = wi % CR;
      const int co = wi / CR;
      const int c = co >> 4, o = co & 15;
      const float4* src = (const float4*)(W + (((size_t)r * CC + c) * CO + o) * CI);
      const float4 f0 = src[0], f1 = src[1];
      bf16x8 v;
      v[0] = (bf16_t)f0.x; v[1] = (bf16_t)f0.y; v[2] = (bf16_t)f0.z; v[3] = (bf16_t)f0.w;
      v[4] = (bf16_t)f1.x; v[5] = (bf16_t)f1.y; v[6] = (bf16_t)f1.z; v[7] = (bf16_t)f1.w;
      *(bf16x8*)(Wt + (size_t)co * CK + r * 8) = v;
    }
  }
  grid.sync();

  for (int it = 0; it < 3; ++it) {
    // ---------------- s + squash: blocks 0..159 = (bt 16, c 10), 8 waves split K ----------------
    if (blk < 160) {
      const int bt = blk & 15, c = blk >> 4;
      const int w = t >> 6, lane = t & 63;
      const int mrow = lane & 15, kg = lane >> 4;
      const int b0 = bt * 16;
      const bf16_t* __restrict__ Bmat = (it == 0) ? Wt : Wts;
      const size_t kbase = (size_t)w * (CK / 8);
      const bf16x8* ap = (const bf16x8*)(xb + (size_t)(b0 + mrow) * CK + kbase) + kg;
      const bf16x8* bp = (const bf16x8*)(Bmat + (size_t)(c * CO + mrow) * CK + kbase) + kg;
      f32x4 acc0 = {0.f, 0.f, 0.f, 0.f}, acc1 = {0.f, 0.f, 0.f, 0.f};
      #pragma unroll 6
      for (int s = 0; s < 36; s += 2) {
        acc0 = __builtin_amdgcn_mfma_f32_16x16x32_bf16(ap[s * 4], bp[s * 4], acc0, 0, 0, 0);
        acc1 = __builtin_amdgcn_mfma_f32_16x16x32_bf16(ap[(s + 1) * 4], bp[(s + 1) * 4], acc1, 0, 0, 0);
      }
      const f32x4 acc = acc0 + acc1;
      #pragma unroll
      for (int reg = 0; reg < 4; ++reg) sm.Ls[w][lane][reg] = acc[reg];
      __syncthreads();
      if (t < 256) {
        const int row = t >> 4, col = t & 15;
        const int l = ((row >> 2) << 4) | col, reg = row & 3;
        float s = 0.f;
        #pragma unroll
        for (int q = 0; q < 8; ++q) s += sm.Ls[q][l][reg];
        if (it == 0) s *= 0.1f;           // uniform c_ij = 1/10
        s += bias[c * CO + col];
        float n2 = s * s;
        #pragma unroll
        for (int m = 1; m < 16; m <<= 1) n2 += __shfl_xor(n2, m);
        const float vv = s * n2 / (1.f + n2) * rsqrtf(n2 + 1e-8f);
        if (it == 2) out[(size_t)(b0 + row) * NCO + c * CO + col] = vv;
        else         vTb[(size_t)(c * CO + col) * CB + b0 + row] = (bf16_t)vv;
      }
    }
    grid.sync();
    if (it == 2) break;

    // ---------------- agree + softmax + prescale: blocks 0..143, halves split classes ----------------
    if (blk < 144) {
      const int r0 = blk * 8;
      const int h = t >> 8;            // class-half 0/1
      const int th = t & 255;
      const int w = th >> 6, lane = th & 63;
      const int mrow = lane & 15, kg = lane >> 4;

      #pragma unroll
      for (int q = 0; q < 10; ++q) {   // stage vTb (5120 bf16x8) into LDS
        const int idx = q * THR + t;
        const int co = idx >> 5, bs = idx & 31;
        const bf16x8 v = ((const bf16x8*)vTb)[idx];
        *(bf16x8*)&sm.vL[co][bs * 8] = v;
      }
      const int m0 = r0 * 8 + w * 16;  // A rows (r,i), K = b = 256
      const bf16x8* ap = (const bf16x8*)(xTb + (size_t)(m0 + mrow) * CB) + kg;
      bf16x8 a[8];
      #pragma unroll
      for (int s = 0; s < 8; ++s) a[s] = ap[s * 4];
      __syncthreads();

      const int o = lane & 15, g = lane >> 4;
      #pragma unroll
      for (int cc = 0; cc < 5; ++cc) {
        const int c = h * 5 + cc;
        f32x4 acc = {0.f, 0.f, 0.f, 0.f};
        #pragma unroll
        for (int s = 0; s < 8; ++s) {
          const bf16x8 bv = *(const bf16x8*)&sm.vL[c * CO + mrow][s * 32 + kg * 8];
          acc = __builtin_amdgcn_mfma_f32_16x16x32_bf16(a[s], bv, acc, 0, 0, 0);
        }
        float p = 0.f;
        #pragma unroll
        for (int reg = 0; reg < 4; ++reg) {
          const int m = g * 4 + reg, rl = m >> 3, i = m & 7;
          p += acc[reg] * W[(((size_t)(r0 + w * 2 + rl) * CC + c) * CO + o) * CI + i];
        }
        #pragma unroll
        for (int msk = 1; msk < 32; msk <<= 1) p += __shfl_xor(p, msk);
        if ((lane & 31) == 0) agrL[w * 2 + (lane >> 5)][c] = p * (1.0f / CB);
      }
      __syncthreads();

      if (t < 8) {
        float nb[CC];
        float mx = -1e30f;
        #pragma unroll
        for (int c = 0; c < CC; ++c) {
          nb[c] = (it == 0 ? 0.f : bL[t][c]) + agrL[t][c];
          mx = fmaxf(mx, nb[c]);
        }
        float sum = 0.f;
        #pragma unroll
        for (int c = 0; c < CC; ++c) {
          bL[t][c] = nb[c];
          const float e = __expf(nb[c] - mx);
          cwL[t][c] = e;
          sum += e;
        }
        const float inv = 1.f / sum;
        #pragma unroll
        for (int c = 0; c < CC; ++c) cwL[t][c] *= inv;
      }
      __syncthreads();

      #pragma unroll
      for (int q = 0; q < 3; ++q) {    // Wts = Wt * c_ij for this block's 8 r's (1280 slots)
        const int slot = q * THR + t;
        if (slot < 1280) {
          const int co = slot >> 3, rl = slot & 7;
          const float cw = cwL[rl][co >> 4];
          const size_t off = (size_t)co * CK + (r0 + rl) * 8;
          const bf16x8 wv = *(const bf16x8*)(Wt + off);
          bf16x8 ov;
          #pragma unroll
          for (int j = 0; j < 8; ++j) ov[j] = (bf16_t)((float)wv[j] * cw);
          *(bf16x8*)(Wts + off) = ov;
        }
      }
    }
    grid.sync();
  }
}

extern "C" void kernel_launch(void* const* d_in, const int* in_sizes, int n_in,
                              void* d_out, int out_size, void* d_ws, size_t ws_size,
                              hipStream_t stream) {
  const float* x    = (const float*)d_in[0];
  const float* W    = (const float*)d_in[1];
  const float* bias = (const float*)d_in[2];
  float* out = (float*)d_out;

  // ws: xb | xTb | Wt | Wts | vTb  (bf16, ~15.3 MB)
  bf16_t* xb  = (bf16_t*)d_ws;
  bf16_t* xTb = xb  + (size_t)CB * CK;
  bf16_t* Wt  = xTb + (size_t)CB * CK;
  bf16_t* Wts = Wt  + (size_t)NCO * CK;
  bf16_t* vTb = Wts + (size_t)NCO * CK;

  void* args[] = {(void*)&x, (void*)&W, (void*)&bias, (void*)&out,
                  (void*)&xb, (void*)&xTb, (void*)&Wt, (void*)&Wts, (void*)&vTb};
  hipLaunchCooperativeKernel((const void*)k_fused, dim3(GRD), dim3(THR),
                             args, 0, stream);
}

// Round 6
// 86.130 us; speedup vs baseline: 3.3067x; 3.3067x over previous
//
#include <hip/hip_runtime.h>

#define CB 256   // batch
#define CR 1152  // routes
#define CC 10    // class capsules
#define CO 16    // out dim
#define CI 8     // in dim
#define CK (CR*CI)   // 9216
#define NCO (CC*CO)  // 160

typedef __bf16 bf16_t;
typedef __attribute__((ext_vector_type(8))) __bf16 bf16x8;
typedef __attribute__((ext_vector_type(4))) float f32x4;

// ---------------- cvt: x -> xb [b][k] bf16, xTb [k][b] bf16 ; W -> Wt [co][k] bf16 ----------------
__global__ __launch_bounds__(256) void k_cvt(const float* __restrict__ x,
                                             const float* __restrict__ W,
                                             bf16_t* __restrict__ xb,
                                             bf16_t* __restrict__ xTb,
                                             bf16_t* __restrict__ Wt) {
  const int t = threadIdx.x;
  if (blockIdx.x < 1152) {
    // x tile job: 144 k-tiles x 8 b-tiles; tile = 32 b x 64 k (one read -> xb + xTb)
    const int bt = blockIdx.x & 7, kt = blockIdx.x >> 3;
    const int b0 = bt * 32, k0 = kt * 64;
    __shared__ float ldsT[64][33];
    const int row = t >> 3, cv = t & 7;
    const float4* xp = (const float4*)(x + (size_t)(b0 + row) * CK + k0 + cv * 8);
    const float4 f0 = xp[0], f1 = xp[1];
    float vals[8] = {f0.x, f0.y, f0.z, f0.w, f1.x, f1.y, f1.z, f1.w};
    bf16x8 ov;
    #pragma unroll
    for (int j = 0; j < 8; ++j) {
      ov[j] = (bf16_t)vals[j];
      ldsT[cv * 8 + j][row] = vals[j];
    }
    *(bf16x8*)(xb + (size_t)(b0 + row) * CK + k0 + cv * 8) = ov;
    __syncthreads();
    const int kr = t >> 2, bs = t & 3;
    bf16x8 tv;
    #pragma unroll
    for (int j = 0; j < 8; ++j) tv[j] = (bf16_t)ldsT[kr][bs * 8 + j];
    *(bf16x8*)(xTb + (size_t)(k0 + kr) * CB + b0 + bs * 8) = tv;
  } else {
    // W job: 720 blocks, wi over C*O*R = 184320
    const int wi = (blockIdx.x - 1152) * 256 + t;
    const int r = wi % CR;
    const int co = wi / CR;
    const int c = co >> 4, o = co & 15;
    const float4* src = (const float4*)(W + (((size_t)r * CC + c) * CO + o) * CI);
    const float4 f0 = src[0], f1 = src[1];
    bf16x8 v;
    v[0] = (bf16_t)f0.x; v[1] = (bf16_t)f0.y; v[2] = (bf16_t)f0.z; v[3] = (bf16_t)f0.w;
    v[4] = (bf16_t)f1.x; v[5] = (bf16_t)f1.y; v[6] = (bf16_t)f1.z; v[7] = (bf16_t)f1.w;
    *(bf16x8*)(Wt + (size_t)co * CK + r * 8) = v;
  }
}

// ---------------- fused s + squash: 160 blocks x 1024 thr (16-way K-split) ----------------
// XCD-aware decode: xcd gets 2 bt x all 10 c -> per-XCD L2 working set = 2 xb-slices + all Wts ~3.5MB
template<int MODE, bool LAST>
__global__ __launch_bounds__(1024) void k_s(const bf16_t* __restrict__ xb,
                                            const bf16_t* __restrict__ Bmat,
                                            const float* __restrict__ bias,
                                            bf16_t* __restrict__ vTb,
                                            float* __restrict__ out) {
  const int blk = blockIdx.x;
  const int xcd = blk & 7, j = blk >> 3;     // assumes round-robin blk->XCD (perf heuristic only)
  const int bt = xcd * 2 + (j & 1);
  const int c = j >> 1;
  const int t = threadIdx.x;
  const int w = t >> 6, lane = t & 63;       // 16 waves
  const int mrow = lane & 15, kg = lane >> 4;
  const int b0 = bt * 16;
  const size_t kbase = (size_t)w * (CK / 16);   // 576 k per wave = 18 ksteps

  const bf16x8* ap = (const bf16x8*)(xb + (size_t)(b0 + mrow) * CK + kbase) + kg;
  const bf16x8* bp = (const bf16x8*)(Bmat + (size_t)(c * CO + mrow) * CK + kbase) + kg;

  f32x4 acc0 = {0.f, 0.f, 0.f, 0.f}, acc1 = {0.f, 0.f, 0.f, 0.f};
  #pragma unroll
  for (int s = 0; s < 18; s += 2) {
    acc0 = __builtin_amdgcn_mfma_f32_16x16x32_bf16(ap[s * 4], bp[s * 4], acc0, 0, 0, 0);
    acc1 = __builtin_amdgcn_mfma_f32_16x16x32_bf16(ap[(s + 1) * 4], bp[(s + 1) * 4], acc1, 0, 0, 0);
  }
  const f32x4 acc = acc0 + acc1;

  __shared__ float Ls[16][64][4];   // 16 KB
  #pragma unroll
  for (int reg = 0; reg < 4; ++reg) Ls[w][lane][reg] = acc[reg];
  __syncthreads();

  if (t < 256) {
    const int row = t >> 4, col = t & 15;          // row = b-local, col = o
    const int l = ((row >> 2) << 4) | col, reg = row & 3;
    float s = 0.f;
    #pragma unroll
    for (int q = 0; q < 16; ++q) s += Ls[q][l][reg];
    if (MODE == 0) s *= 0.1f;                      // uniform c_ij = 1/10
    s += bias[c * CO + col];
    float n2 = s * s;
    #pragma unroll
    for (int m = 1; m < 16; m <<= 1) n2 += __shfl_xor(n2, m);
    const float vv = s * n2 / (1.f + n2) * rsqrtf(n2 + 1e-8f);
    if (LAST) out[(size_t)(b0 + row) * NCO + c * CO + col] = vv;
    else      vTb[(size_t)(c * CO + col) * CB + b0 + row] = (bf16_t)vv;
  }
}

// ---------------- agree + softmax + W-prescale: 144 blocks x 512 thr (class-halves) ----------------
// G[(r,i),(c,o)] = sum_b xTb[(r,i)][b] * vTb[(c,o)][b]  via MFMA (K=256)
template<bool FIRST>
__global__ __launch_bounds__(512) void k_asc(const bf16_t* __restrict__ xTb,
                                             const bf16_t* __restrict__ vTb,
                                             const float* __restrict__ W,
                                             const bf16_t* __restrict__ Wt,
                                             float* __restrict__ b_ij,
                                             bf16_t* __restrict__ Wts) {
  const int r0 = blockIdx.x * 8;
  const int t = threadIdx.x;
  const int h = t >> 8;            // class-half 0/1
  const int th = t & 255;
  const int w = th >> 6, lane = th & 63;
  const int mrow = lane & 15, kg = lane >> 4;

  __shared__ __align__(16) unsigned short vL[NCO][CB + 8];  // 84.5 KB
  __shared__ float agrL[8][CC];
  __shared__ float cwL[8][CC];

  // stage vTb (80 KB = 5120 bf16x8) into LDS
  #pragma unroll
  for (int q = 0; q < 10; ++q) {
    const int idx = q * 512 + t;
    const int co = idx >> 5, bs = idx & 31;
    const bf16x8 v = ((const bf16x8*)vTb)[idx];
    *(bf16x8*)&vL[co][bs * 8] = v;
  }

  // A fragments: full K=256, rows (r,i) for this wave's 2 r's (both halves load same)
  const int m0 = r0 * 8 + w * 16;
  const bf16x8* ap = (const bf16x8*)(xTb + (size_t)(m0 + mrow) * CB) + kg;
  bf16x8 a[8];
  #pragma unroll
  for (int s = 0; s < 8; ++s) a[s] = ap[s * 4];
  __syncthreads();

  const int o = lane & 15, g = lane >> 4;
  #pragma unroll
  for (int cc = 0; cc < 5; ++cc) {
    const int c = h * 5 + cc;
    f32x4 acc = {0.f, 0.f, 0.f, 0.f};
    #pragma unroll
    for (int s = 0; s < 8; ++s) {
      const bf16x8 bv = *(const bf16x8*)&vL[c * CO + mrow][s * 32 + kg * 8];
      acc = __builtin_amdgcn_mfma_f32_16x16x32_bf16(a[s], bv, acc, 0, 0, 0);
    }
    float p = 0.f;
    #pragma unroll
    for (int reg = 0; reg < 4; ++reg) {
      const int m = g * 4 + reg, rl = m >> 3, i = m & 7;
      p += acc[reg] * W[(((size_t)(r0 + w * 2 + rl) * CC + c) * CO + o) * CI + i];
    }
    #pragma unroll
    for (int msk = 1; msk < 32; msk <<= 1) p += __shfl_xor(p, msk);
    if ((lane & 31) == 0) agrL[w * 2 + (lane >> 5)][c] = p * (1.0f / CB);
  }
  __syncthreads();

  if (t < 8) {
    const int r = r0 + t;
    float nb[CC];
    float mx = -1e30f;
    #pragma unroll
    for (int c = 0; c < CC; ++c) {
      nb[c] = (FIRST ? 0.f : b_ij[r * CC + c]) + agrL[t][c];
      mx = fmaxf(mx, nb[c]);
    }
    float sum = 0.f;
    #pragma unroll
    for (int c = 0; c < CC; ++c) {
      b_ij[r * CC + c] = nb[c];
      const float e = __expf(nb[c] - mx);
      cwL[t][c] = e;
      sum += e;
    }
    const float inv = 1.f / sum;
    #pragma unroll
    for (int c = 0; c < CC; ++c) cwL[t][c] *= inv;
  }
  __syncthreads();

  // Wts[co][k] = Wt[co][k] * cw[r(k), c(co)] for this block's 8 r's (1280 bf16x8 slots)
  #pragma unroll
  for (int q = 0; q < 3; ++q) {
    const int slot = q * 512 + t;
    if (slot < 1280) {
      const int co = slot >> 3, rl = slot & 7;
      const float cw = cwL[rl][co >> 4];
      const size_t off = (size_t)co * CK + (r0 + rl) * 8;
      const bf16x8 wv = *(const bf16x8*)(Wt + off);
      bf16x8 ov;
      #pragma unroll
      for (int jj = 0; jj < 8; ++jj) ov[jj] = (bf16_t)((float)wv[jj] * cw);
      *(bf16x8*)(Wts + off) = ov;
    }
  }
}

extern "C" void kernel_launch(void* const* d_in, const int* in_sizes, int n_in,
                              void* d_out, int out_size, void* d_ws, size_t ws_size,
                              hipStream_t stream) {
  const float* x    = (const float*)d_in[0];
  const float* W    = (const float*)d_in[1];
  const float* bias = (const float*)d_in[2];
  float* out = (float*)d_out;

  // ws: xb | xTb | Wt | Wts | vTb (bf16) | b_ij (f32)  ~15.3 MB
  bf16_t* xb  = (bf16_t*)d_ws;
  bf16_t* xTb = xb  + (size_t)CB * CK;
  bf16_t* Wt  = xTb + (size_t)CB * CK;
  bf16_t* Wts = Wt  + (size_t)NCO * CK;
  bf16_t* vTb = Wts + (size_t)NCO * CK;
  float*  b_ij = (float*)(vTb + (size_t)NCO * CB);

  k_cvt<<<1872, 256, 0, stream>>>(x, W, xb, xTb, Wt);

  // iter 0: uniform c_ij (0.1 post-scale), then agree+softmax+prescale
  k_s<0, false><<<160, 1024, 0, stream>>>(xb, Wt, bias, vTb, out);
  k_asc<true><<<144, 512, 0, stream>>>(xTb, vTb, W, Wt, b_ij, Wts);

  // iter 1
  k_s<1, false><<<160, 1024, 0, stream>>>(xb, Wts, bias, vTb, out);
  k_asc<false><<<144, 512, 0, stream>>>(xTb, vTb, W, Wt, b_ij, Wts);

  // iter 2 (final)
  k_s<1, true><<<160, 1024, 0, stream>>>(xb, Wts, bias, vTb, out);
}